// Round 1
// baseline (854.324 us; speedup 1.0000x reference)
//
#include <hip/hip_runtime.h>

// SimpleRNN: B=16384, T=2048, I=1, H=20, O=1, fp32.
//
// Round-6 change (round 5: 619.6 us, ~726 cyc/step at 1 wave/SIMD; halving
// FMA count r4->r5 gained only 3% => issue/latency-bound with idle slots,
// not FMA-throughput-bound):
//  (a) 8 threads per batch element (131072 threads = 2048 waves = 2
//      waves/SIMD): thread (part, half) owns rows part*5..+4 and COLUMNS
//      half*10..half*10+9. Per-thread step work: 25 pk_fma (was 50),
//      10 DPP movs (was 20), acc chain 6-deep (was 11). Cross-half reduce
//      via 2x ds_bpermute + add per row, which ALSO redistributes row
//      groups so quad-lane q of a half-hf quad holds rc[hf*10+q*5+k] --
//      exactly what its quad DPP-broadcasts next step (source row group
//      s = (part + 2*half) & 3; only quad-lanes 0/1 are broadcast sources).
//  (b) tanh folded into weights: tanh(a) = 1 - 2*rcp(exp2(K*a)+1),
//      K = 2*log2(e). Pre-scale W_hh -> -2K*W, W_ih -> K*W_ih, fold
//      K*rowsum(W_hh) into bias; carry rc = rcp(exp2(acc)+1) as state.
//      Activation: 3 insts/row (was 5). h reconstructed in epilogue.

#define RNN_T 2048
#define RNN_H 20
#define RNN_B 16384
#define NT4   (RNN_T / 4)

typedef float v2f __attribute__((ext_vector_type(2)));

template <int CTRL>
__device__ __forceinline__ float qb(float v) {
    // v_mov_b32_dpp quad_perm broadcast: CTRL = q * 0x55 broadcasts quad-lane q.
    return __builtin_bit_cast(
        float, __builtin_amdgcn_mov_dpp(__builtin_bit_cast(int, v), CTRL, 0xF, 0xF, true));
}

__device__ __forceinline__ float bperm(int addr, float v) {
    return __builtin_bit_cast(
        float, __builtin_amdgcn_ds_bpermute(addr, __builtin_bit_cast(int, v)));
}

// Scaled weight pairs for row R (5 column-pairs over this thread's 10 cols),
// plus folded bias. Raw row sum (this half's 10 cols) folds into bias with
// coefficient +K; weights get -2K (from h = 1 - 2*rc).
#define DECLW_ROW(R)                                                             \
    v2f wp##R##_0, wp##R##_1, wp##R##_2, wp##R##_3, wp##R##_4;                   \
    v2f biasP##R, wihP##R;                                                       \
    {                                                                            \
        const float* wr = W_hh + (part * 5 + (R)) * RNN_H + hf * 10;             \
        v2f a0 = *(const v2f*)(wr + 0);                                          \
        v2f a1 = *(const v2f*)(wr + 2);                                          \
        v2f a2 = *(const v2f*)(wr + 4);                                          \
        v2f a3 = *(const v2f*)(wr + 6);                                          \
        v2f a4 = *(const v2f*)(wr + 8);                                          \
        float rs = a0.x + a0.y + a1.x + a1.y + a2.x + a2.y + a3.x + a3.y +       \
                   a4.x + a4.y;                                                  \
        wp##R##_0 = a0 * WS;                                                     \
        wp##R##_1 = a1 * WS;                                                     \
        wp##R##_2 = a2 * WS;                                                     \
        wp##R##_3 = a3 * WS;                                                     \
        wp##R##_4 = a4 * WS;                                                     \
        const int r = part * 5 + (R);                                            \
        float bb = ((hf == 0) ? KK * (b_ih[r] + b_hh[r]) : 0.0f) + KK * rs;      \
        biasP##R.x = bb;                                                         \
        biasP##R.y = 0.0f;                                                       \
        wihP##R.x  = (hf == 0) ? KK * W_ih[r] : 0.0f;                            \
        wihP##R.y  = 0.0f;                                                       \
    }

// One column-pair block: build rc pair (2 DPP movs), fold into all 5 acc pairs
// with one v_pk_fma_f32 each.
#define PBLK(I, CA, RA, CB, RB)                                                  \
    {                                                                            \
        v2f ha;                                                                  \
        ha.x = qb<CA>(RA);                                                       \
        ha.y = qb<CB>(RB);                                                       \
        acc0 = __builtin_elementwise_fma(wp0_##I, ha, acc0);                     \
        acc1 = __builtin_elementwise_fma(wp1_##I, ha, acc1);                     \
        acc2 = __builtin_elementwise_fma(wp2_##I, ha, acc2);                     \
        acc3 = __builtin_elementwise_fma(wp3_##I, ha, acc3);                     \
        acc4 = __builtin_elementwise_fma(wp4_##I, ha, acc4);                     \
    }

// One RNN step. rc0..rc4 hold rc = rcp(exp2(acc)+1) for rows s*5..s*5+4
// (s = (part + 2*half) & 3). Broadcast sources: quad-lane q register rc_k
// = rc[half*10 + q*5 + k], so column j (0..9 local) comes from quad-lane
// j/5, register j%5 -- wave-uniform ctrls 0x00 / 0x55 only.
#define STEP(XS)                                                                 \
    do {                                                                         \
        v2f xx;                                                                  \
        xx.x = (XS);                                                             \
        xx.y = (XS);                                                             \
        v2f acc0 = __builtin_elementwise_fma(wihP0, xx, biasP0);                 \
        v2f acc1 = __builtin_elementwise_fma(wihP1, xx, biasP1);                 \
        v2f acc2 = __builtin_elementwise_fma(wihP2, xx, biasP2);                 \
        v2f acc3 = __builtin_elementwise_fma(wihP3, xx, biasP3);                 \
        v2f acc4 = __builtin_elementwise_fma(wihP4, xx, biasP4);                 \
        PBLK(0, 0x00, rc0, 0x00, rc1)                                            \
        PBLK(1, 0x00, rc2, 0x00, rc3)                                            \
        PBLK(2, 0x00, rc4, 0x55, rc0)                                            \
        PBLK(3, 0x55, rc1, 0x55, rc2)                                            \
        PBLK(4, 0x55, rc3, 0x55, rc4)                                            \
        float s0 = acc0.x + acc0.y;                                              \
        float s1 = acc1.x + acc1.y;                                              \
        float s2 = acc2.x + acc2.y;                                              \
        float s3 = acc3.x + acc3.y;                                              \
        float s4 = acc4.x + acc4.y;                                              \
        float f0 = bperm(addrA, s0) + bperm(addrB, s0);                          \
        float f1 = bperm(addrA, s1) + bperm(addrB, s1);                          \
        float f2 = bperm(addrA, s2) + bperm(addrB, s2);                          \
        float f3 = bperm(addrA, s3) + bperm(addrB, s3);                          \
        float f4 = bperm(addrA, s4) + bperm(addrB, s4);                          \
        rc0 = __builtin_amdgcn_rcpf(__builtin_amdgcn_exp2f(f0) + 1.0f);          \
        rc1 = __builtin_amdgcn_rcpf(__builtin_amdgcn_exp2f(f1) + 1.0f);          \
        rc2 = __builtin_amdgcn_rcpf(__builtin_amdgcn_exp2f(f2) + 1.0f);          \
        rc3 = __builtin_amdgcn_rcpf(__builtin_amdgcn_exp2f(f3) + 1.0f);          \
        rc4 = __builtin_amdgcn_rcpf(__builtin_amdgcn_exp2f(f4) + 1.0f);          \
    } while (0)

__attribute__((amdgpu_flat_work_group_size(256, 256), amdgpu_waves_per_eu(2, 2)))
__global__ void rnn_fwd(const float* __restrict__ x,
                        const float* __restrict__ W_ih,
                        const float* __restrict__ W_hh,
                        const float* __restrict__ b_ih,
                        const float* __restrict__ b_hh,
                        const float* __restrict__ W_fc,
                        const float* __restrict__ b_fc,
                        float* __restrict__ out) {
    const int gid  = blockIdx.x * blockDim.x + threadIdx.x;
    const int b    = gid >> 3;        // batch element (8 threads each)
    const int oct  = gid & 7;         // octet lane
    const int part = oct & 3;         // row group: rows part*5..part*5+4
    const int hf   = oct >> 2;        // column half: cols hf*10..hf*10+9

    // Row group this lane RECEIVES after the bpermute reduce/redistribute.
    const int s = (part + 2 * hf) & 3;

    const int lane  = threadIdx.x & 63;
    const int addrA = ((lane & ~7) + s) << 2;   // octet lane s  (half-0 partial)
    const int addrB = addrA + 16;               // octet lane s+4 (half-1 partial)

    const float KK = 2.885390081777927f;   // 2*log2(e)
    const float WS = -2.0f * KK;           // W_hh scale: -2K

    DECLW_ROW(0) DECLW_ROW(1) DECLW_ROW(2) DECLW_ROW(3) DECLW_ROW(4)

    // rc = 0.5 <=> h = 0.
    float rc0 = 0.5f, rc1 = 0.5f, rc2 = 0.5f, rc3 = 0.5f, rc4 = 0.5f;

    const float4* x4 = (const float4*)(x + (size_t)b * RNN_T);

    float4 xv = x4[0];
#pragma unroll 1
    for (int t4 = 0; t4 < NT4; ++t4) {
        const int tn = (t4 + 1 < NT4) ? (t4 + 1) : t4;
        const float4 xn = x4[tn];
        STEP(xv.x);
        STEP(xv.y);
        STEP(xv.z);
        STEP(xv.w);
        xv = xn;
    }

    // Reconstruct h = 1 - 2*rc for the rows this lane holds (group s), dot
    // with W_fc, quad-reduce (lanes 0-3 hold s = 0..3 => all 20 rows once).
    const float h0 = fmaf(-2.0f, rc0, 1.0f);
    const float h1 = fmaf(-2.0f, rc1, 1.0f);
    const float h2 = fmaf(-2.0f, rc2, 1.0f);
    const float h3 = fmaf(-2.0f, rc3, 1.0f);
    const float h4 = fmaf(-2.0f, rc4, 1.0f);
    const int o0 = s * 5;
    float p = fmaf(h0, W_fc[o0 + 0], 0.0f);
    p = fmaf(h1, W_fc[o0 + 1], p);
    p = fmaf(h2, W_fc[o0 + 2], p);
    p = fmaf(h3, W_fc[o0 + 3], p);
    p = fmaf(h4, W_fc[o0 + 4], p);
    p += __shfl_xor(p, 1, 64);
    p += __shfl_xor(p, 2, 64);
    if (oct == 0) {
        const float z = p + b_fc[0];
        const float e = __builtin_amdgcn_exp2f(-1.4426950408889634f * z);
        out[b] = __builtin_amdgcn_rcpf(1.0f + e);
    }
}

extern "C" void kernel_launch(void* const* d_in, const int* in_sizes, int n_in,
                              void* d_out, int out_size, void* d_ws, size_t ws_size,
                              hipStream_t stream) {
    const float* x    = (const float*)d_in[0];
    const float* W_ih = (const float*)d_in[1];
    const float* W_hh = (const float*)d_in[2];
    const float* b_ih = (const float*)d_in[3];
    const float* b_hh = (const float*)d_in[4];
    const float* W_fc = (const float*)d_in[5];
    const float* b_fc = (const float*)d_in[6];
    float* out = (float*)d_out;

    const int threads = RNN_B * 8;  // 131072 = 2048 waves = 2 waves/SIMD
    const int block   = 256;
    rnn_fwd<<<threads / block, block, 0, stream>>>(x, W_ih, W_hh, b_ih, b_hh,
                                                   W_fc, b_fc, out);
}